// Round 2
// baseline (2394.752 us; speedup 1.0000x reference)
//
#include <hip/hip_runtime.h>
#include <cstdint>
#include <cstddef>

// ---------------------------------------------------------------------------
// TinyViT block (window attention + dwconv/BN + MLP) for MI355X / gfx950.
// Token order: token = win*49 + n, win = ((b*8+wh)*8+ww), n = r*7+c,
// spatial (h,w) = (wh*7+r, ww*7+c). 56 = 8*7 (no padding).
//
// R4 (= R3 structure + workspace fix):
//   - R3 crashed: it hard-allocated the 698MB single-chunk layout, but
//     ws_size is only ~236-390MB (R2 ran at MC=25088). R4 restores dynamic
//     chunking and cuts per-token scratch to 5376B:
//       * attn output reuses the xn region (dead after qkv GEMM)
//       * proj GEMM accumulates IN-PLACE (bf16) into persistent seqtok
//         (gather pre-writes raw-x tokens there; same precision as R2,
//         which also stored seq as bf16)
//       * mlp2 accumulates IN-PLACE (fp32) into seq2f -> no ptmp
//   - Window-ROW blocking everywhere: a block owns (b,wh) = 8 windows =
//     rows [7wh,7wh+7) x 56 cols; per channel that is 392 contiguous
//     floats in NCHW, so every transpose coalesces (old per-window
//     transforms produced 28B runs -> 2.3TB/s scatter kernels).
//   - Token-major dwconv (halo from q+-1 window-rows of seqtok) kills the
//     NCHW seq2 round-trip; final scatter is a pure coalesced copy.
// Pipeline:
//   ln_stats; per chunk: gather(x)->xn,seqtok ; qkv gemm ; attn->xn ;
//   proj gemm (in-place += seqtok) ; then per chunk: dwconv(seqtok+halo)
//   ->xn,seq2f ; mlp1 ; mlp2 (in-place += seq2f) ; scatter(seq2f)->out.
// ---------------------------------------------------------------------------

typedef __bf16 bf16x8 __attribute__((ext_vector_type(8)));
typedef float  f32x4  __attribute__((ext_vector_type(4)));

#define DEVI __device__ __forceinline__

static constexpr int   C_    = 384;
static constexpr int   HW_   = 3136;      // 56*56
static constexpr int   NB_   = 32;        // batch
static constexpr int   NTOK  = 100352;    // 32*3136
static constexpr float EPS_  = 1e-5f;
static constexpr float ASCAL = 0.17677669529663689f;  // 32^-0.5

DEVI void gld16(const void* g, void* l) {
  __builtin_amdgcn_global_load_lds((__attribute__((address_space(1))) void*)(g),
                                   (__attribute__((address_space(3))) void*)(l),
                                   16, 0, 0);
}

// n_local in [0,392): ww*49 + r*7 + c  ->  px = r*56 + ww*7 + c
DEVI int px_of(int nl) {
  int ww = nl / 49, nn = nl - ww * 49;
  int r  = nn / 7,  c  = nn - r * 7;
  return r * 56 + ww * 7 + c;
}

// ---------------------------------------------------------------------------
// GEMM: C[m,n] = epi( sum_k A[m,k]*Bt[n,k] + bias[n] )
// EPI: 0 = bf16 store
//      1 = bf16 store, exact gelu
//      3 = bf16 IN-PLACE accumulate (outp[m,n] += v, bf16)
//      4 = f32  IN-PLACE accumulate (outp[m,n] += v, fp32)
// ---------------------------------------------------------------------------
template <int EPI>
__global__ __launch_bounds__(256)
void gemm_bt(const __bf16* __restrict__ A, const __bf16* __restrict__ Bt,
             const float* __restrict__ bias, void* __restrict__ outp,
             int M, int N, int K)
{
  __shared__ __align__(16) __bf16 As[128 * 32];
  __shared__ __align__(16) __bf16 Bs[128 * 32];

  const int tid  = threadIdx.x;
  const int lane = tid & 63;
  const int wave = tid >> 6;
  const int quad = lane >> 4;
  const int l16  = lane & 15;
  const int wr   = (wave >> 1) * 64;
  const int wc   = (wave & 1) * 64;
  const size_t m0 = (size_t)blockIdx.y * 128;
  const size_t n0 = (size_t)blockIdx.x * 128;

  const int srow = tid >> 2;
  const int skc  = (tid & 3) * 8;
  const __bf16* ga0 = A  + (m0 + srow) * (size_t)K + skc;
  const __bf16* ga1 = ga0 + (size_t)64 * K;
  const __bf16* gb0 = Bt + (n0 + srow) * (size_t)K + skc;
  const __bf16* gb1 = gb0 + (size_t)64 * K;
  __bf16* la0 = As + tid * 8;
  __bf16* la1 = As + 2048 + tid * 8;
  __bf16* lb0 = Bs + tid * 8;
  __bf16* lb1 = Bs + 2048 + tid * 8;

  f32x4 acc[4][4] = {};

  const int kiters = K >> 5;
  for (int kb = 0; kb < kiters; ++kb) {
    gld16(ga0, la0); gld16(ga1, la1);
    gld16(gb0, lb0); gld16(gb1, lb1);
    ga0 += 32; ga1 += 32; gb0 += 32; gb1 += 32;
    __syncthreads();
    bf16x8 af[4], bfr[4];
#pragma unroll
    for (int i = 0; i < 4; ++i)
      af[i] = *(const bf16x8*)(As + (wr + i * 16 + l16) * 32 + quad * 8);
#pragma unroll
    for (int j = 0; j < 4; ++j)
      bfr[j] = *(const bf16x8*)(Bs + (wc + j * 16 + l16) * 32 + quad * 8);
#pragma unroll
    for (int i = 0; i < 4; ++i)
#pragma unroll
      for (int j = 0; j < 4; ++j)
        acc[i][j] = __builtin_amdgcn_mfma_f32_16x16x32_bf16(af[i], bfr[j], acc[i][j], 0, 0, 0);
    __syncthreads();
  }

  // C/D layout: col = lane&15, row = (lane>>4)*4 + reg   [measured m89/m91]
#pragma unroll
  for (int j = 0; j < 4; ++j) {
    const size_t ng = n0 + wc + j * 16 + l16;
    const float bv = bias[ng];
#pragma unroll
    for (int i = 0; i < 4; ++i) {
      const size_t mg = m0 + wr + i * 16 + quad * 4;
#pragma unroll
      for (int r = 0; r < 4; ++r) {
        float v = acc[i][j][r] + bv;
        const size_t idx = (mg + r) * (size_t)N + ng;
        if (EPI == 1) v = 0.5f * v * (1.0f + erff(v * 0.70710678118654752f));
        if (EPI == 3) {
          __bf16* o = (__bf16*)outp;
          v += (float)o[idx];
          o[idx] = (__bf16)v;
        } else if (EPI == 4) {
          float* o = (float*)outp;
          v += o[idx];
          o[idx] = v;
        } else {
          ((__bf16*)outp)[idx] = (__bf16)v;
        }
      }
    }
  }
}

// ---------------------------------------------------------------------------
// Per-token LayerNorm statistics (x in NCHW, coalesced over hw).
// ---------------------------------------------------------------------------
__global__ __launch_bounds__(256)
void ln_stats(const float* __restrict__ x, float* __restrict__ mean,
              float* __restrict__ rstd)
{
  const int b  = blockIdx.y;
  const int hw = blockIdx.x * 256 + threadIdx.x;
  if (hw >= HW_) return;
  const float* p = x + (size_t)b * (C_ * HW_) + hw;
  float s = 0.f, ss = 0.f;
  for (int c = 0; c < C_; ++c) {
    float v = p[(size_t)c * HW_];
    s += v; ss = fmaf(v, v, ss);
  }
  float mu  = s * (1.0f / C_);
  float var = ss * (1.0f / C_) - mu * mu;
  mean[b * HW_ + hw] = mu;
  rstd[b * HW_ + hw] = rsqrtf(var + EPS_);
}

// ---------------------------------------------------------------------------
// fp32 weight -> bf16 copies (qkv_w, proj_w, w1, w2), one launch.
// ---------------------------------------------------------------------------
__global__ __launch_bounds__(256)
void convert_weights(const float* __restrict__ a, const float* __restrict__ b,
                     const float* __restrict__ c, const float* __restrict__ d,
                     __bf16* __restrict__ oa, __bf16* __restrict__ ob,
                     __bf16* __restrict__ oc, __bf16* __restrict__ od)
{
  int i = blockIdx.x * 256 + threadIdx.x;
  if      (i < 442368)  oa[i] = (__bf16)a[i];
  else if (i < 589824)  ob[i - 442368]  = (__bf16)b[i - 442368];
  else if (i < 1179648) oc[i - 589824]  = (__bf16)c[i - 589824];
  else if (i < 1769472) od[i - 1179648] = (__bf16)d[i - 1179648];
}

// ---------------------------------------------------------------------------
// Window-row gather: NCHW fp32 -> token-major. Emits LN'd bf16 (xn,
// chunk-local) AND raw bf16 tokens (seqtok, GLOBAL index — the proj GEMM
// accumulates the shortcut in-place there).
// grid = (12 channel-chunks of 32, wrc window-rows). Reads: 392-float
// contiguous runs per channel; writes: 64B per-token runs.
// ---------------------------------------------------------------------------
__global__ __launch_bounds__(256)
void winrow_gather_ln(const float* __restrict__ x, const float* __restrict__ mean,
                      const float* __restrict__ rstd, const float* __restrict__ gamma,
                      const float* __restrict__ beta, __bf16* __restrict__ xn,
                      __bf16* __restrict__ seqtok, int q0)
{
  const int by = blockIdx.y;
  const int q  = q0 + by;               // global window-row: b*8 + wh
  const int cb = blockIdx.x * 32;
  const int b  = q >> 3, wh = q & 7;
  const int tid = threadIdx.x;
  __shared__ float tile[32 * 393];      // [ch][px], stride 393 (9*ch mod 32 distinct)
  __shared__ float ms[392], rs[392];

  for (int i = tid; i < 392; i += 256) {
    ms[i] = mean[b * HW_ + wh * 392 + i];
    rs[i] = rstd[b * HW_ + wh * 392 + i];
  }
  const float* xs = x + ((size_t)b * C_ + cb) * HW_ + wh * 392;
  for (int e = tid; e < 32 * 392; e += 256) {      // i fast -> coalesced 1KB/wave
    int ch = e / 392, i = e - ch * 392;
    tile[ch * 393 + i] = xs[(size_t)ch * HW_ + i];
  }
  __syncthreads();

  const int ch = tid & 31;
  const float g  = gamma[cb + ch];
  const float bt = beta[cb + ch];
  __bf16* xo = xn     + ((size_t)by * 392) * 384 + cb + ch;   // chunk-local
  __bf16* sr = seqtok + ((size_t)q  * 392) * 384 + cb + ch;   // global
  for (int n = tid >> 5; n < 392; n += 8) {
    int px = px_of(n);
    float v = tile[ch * 393 + px];
    sr[(size_t)n * 384] = (__bf16)v;
    xo[(size_t)n * 384] = (__bf16)((v - ms[px]) * rs[px] * g + bt);
  }
}

// ---------------------------------------------------------------------------
// Window attention, one wave per (window, head). K,V staged fp32 in LDS
// (bf16x8 vector staging loads); uniform-address f32x4 LDS reads broadcast.
// ---------------------------------------------------------------------------
__global__ __launch_bounds__(64)
void attn_win(const __bf16* __restrict__ qkv, const float* __restrict__ btab,
              __bf16* __restrict__ attn_out)
{
  const int head = blockIdx.x;
  const int wl   = blockIdx.y;
  const int lane = threadIdx.x;

  __shared__ __align__(16) float ks[49 * 32];
  __shared__ __align__(16) float vs[49 * 32];
  __shared__ float bs[169];

  const __bf16* base = qkv + (size_t)wl * (49 * 1152) + head * 32;
  for (int e = lane; e < 196; e += 64) {           // 49 tokens x 4 groups of 8
    int n = e >> 2, g4 = e & 3;
    const __bf16* rp = base + (size_t)n * 1152;
    bf16x8 kk = *(const bf16x8*)(rp + 384 + g4 * 8);
    bf16x8 vv = *(const bf16x8*)(rp + 768 + g4 * 8);
    float* kd = ks + n * 32 + g4 * 8;
    float* vd = vs + n * 32 + g4 * 8;
#pragma unroll
    for (int u = 0; u < 8; ++u) { kd[u] = (float)kk[u]; vd[u] = (float)vv[u]; }
  }
  for (int e = lane; e < 169; e += 64) bs[e] = btab[e * 12 + head];
  __syncthreads();

  if (lane >= 49) return;
  const int ri = lane / 7, ci = lane % 7;

  f32x4 q4[8];
  {
    const __bf16* qp = base + (size_t)lane * 1152;
#pragma unroll
    for (int g = 0; g < 4; ++g) {
      bf16x8 t = *(const bf16x8*)(qp + g * 8);
#pragma unroll
      for (int u = 0; u < 8; ++u) q4[g * 2 + (u >> 2)][u & 3] = (float)t[u] * ASCAL;
    }
  }

  float p[49];
  float mx = -1e30f;
#pragma unroll
  for (int j = 0; j < 49; ++j) {
    float s = bs[(ri - j / 7 + 6) * 13 + (ci - j % 7 + 6)];
    const f32x4* kj = (const f32x4*)(ks + j * 32);
    f32x4 a0 = {0.f, 0.f, 0.f, 0.f}, a1 = {0.f, 0.f, 0.f, 0.f};
#pragma unroll
    for (int dq = 0; dq < 8; dq += 2) {
      f32x4 k0 = kj[dq], k1 = kj[dq + 1];
#pragma unroll
      for (int u = 0; u < 4; ++u) {
        a0[u] = fmaf(q4[dq][u],     k0[u], a0[u]);
        a1[u] = fmaf(q4[dq + 1][u], k1[u], a1[u]);
      }
    }
    s += (a0[0] + a0[1]) + (a0[2] + a0[3]) + (a1[0] + a1[1]) + (a1[2] + a1[3]);
    p[j] = s;
    mx = fmaxf(mx, s);
  }
  float sum = 0.f;
#pragma unroll
  for (int j = 0; j < 49; ++j) { float e = __expf(p[j] - mx); p[j] = e; sum += e; }
  const float inv = 1.0f / sum;

  f32x4 o4[8];
#pragma unroll
  for (int dq = 0; dq < 8; ++dq) o4[dq] = (f32x4){0.f, 0.f, 0.f, 0.f};
#pragma unroll
  for (int j = 0; j < 49; ++j) {
    const float pj = p[j];
    const f32x4* vj = (const f32x4*)(vs + j * 32);
#pragma unroll
    for (int dq = 0; dq < 8; ++dq) {
      f32x4 vv = vj[dq];
#pragma unroll
      for (int u = 0; u < 4; ++u) o4[dq][u] = fmaf(pj, vv[u], o4[dq][u]);
    }
  }
  __bf16* op = attn_out + ((size_t)wl * 49 + lane) * 384 + head * 32;
#pragma unroll
  for (int g = 0; g < 4; ++g) {
    bf16x8 t;
#pragma unroll
    for (int u = 0; u < 8; ++u) t[u] = (__bf16)(o4[g * 2 + (u >> 2)][u & 3] * inv);
    *(bf16x8*)(op + g * 8) = t;
  }
}

// ---------------------------------------------------------------------------
// Depthwise 3x3 conv (pad 1) + inference BN, fully token-major.
// Block = (channel-chunk of 32, window-row). Stages rows [7wh-1, 7wh+7]
// (halo from window-rows q-1/q+1 of the GLOBAL seqtok; zeros at image
// edges) in LDS fp32, 9-tap, writes bf16 tokens (MLP input, chunk-local)
// + fp32 tokens (seq2 residual, chunk-local).
// LDS 32*505*4 = 64,640B (< 64KB); stride 505 -> conflict-free tap reads.
// ---------------------------------------------------------------------------
__global__ __launch_bounds__(256)
void dwconv_winrow(const __bf16* __restrict__ seqtok, const float* __restrict__ cw,
                   const float* __restrict__ g, const float* __restrict__ bta,
                   const float* __restrict__ mn, const float* __restrict__ vr,
                   __bf16* __restrict__ xn, float* __restrict__ seq2f, int q0)
{
  const int by = blockIdx.y;
  const int q  = q0 + by;               // global window-row
  const int cb = blockIdx.x * 32;
  const int wh = q & 7;
  const int tid = threadIdx.x;
  __shared__ float tile[32 * 505];      // [ch][9*56], stride 505

  const size_t tg = (size_t)q  * 392;   // global token base
  const size_t tl = (size_t)by * 392;   // chunk-local token base

  // main slab: spatial rows 7wh..7wh+6 -> tile rows 1..7
  for (int e = tid; e < 392 * 4; e += 256) {       // token x 4 groups of 8ch
    int nl = e >> 2, gg = e & 3;
    bf16x8 t = *(const bf16x8*)(seqtok + (tg + nl) * 384 + cb + gg * 8);
    int px = px_of(nl) + 56;
#pragma unroll
    for (int u = 0; u < 8; ++u) tile[(gg * 8 + u) * 505 + px] = (float)t[u];
  }
  // halo rows 0 and 8
  for (int e = tid; e < 224; e += 256) {           // 56 cols x 4 groups
    int w = e >> 2, gg = e & 3;
    int ww = w / 7, c = w - ww * 7;
    float tv[8], bv[8];
    if (wh > 0) {
      bf16x8 t = *(const bf16x8*)(seqtok + ((size_t)(q - 1) * 392 + ww * 49 + 42 + c) * 384 + cb + gg * 8);
#pragma unroll
      for (int u = 0; u < 8; ++u) tv[u] = (float)t[u];
    } else {
#pragma unroll
      for (int u = 0; u < 8; ++u) tv[u] = 0.f;
    }
    if (wh < 7) {
      bf16x8 t = *(const bf16x8*)(seqtok + ((size_t)(q + 1) * 392 + ww * 49 + c) * 384 + cb + gg * 8);
#pragma unroll
      for (int u = 0; u < 8; ++u) bv[u] = (float)t[u];
    } else {
#pragma unroll
      for (int u = 0; u < 8; ++u) bv[u] = 0.f;
    }
#pragma unroll
    for (int u = 0; u < 8; ++u) {
      tile[(gg * 8 + u) * 505 + w]       = tv[u];
      tile[(gg * 8 + u) * 505 + 448 + w] = bv[u];
    }
  }
  __syncthreads();

  const int ch = tid & 31;
  float wreg[9];
#pragma unroll
  for (int k = 0; k < 9; ++k) wreg[k] = cw[(cb + ch) * 9 + k];
  const float sc = g[cb + ch] * rsqrtf(vr[cb + ch] + EPS_);
  const float bb = bta[cb + ch] - mn[cb + ch] * sc;

  __bf16* xo = xn    + tl * 384 + cb + ch;
  float*  so = seq2f + tl * 384 + cb + ch;
  for (int nl = tid >> 5; nl < 392; nl += 8) {
    int ww = nl / 49, nn = nl - ww * 49;
    int rr = nn / 7,  cc = nn - rr * 7;
    int w  = ww * 7 + cc;
    const float* t0 = tile + ch * 505 + rr * 56 + w;
    float a = 0.f;
    const bool wl_ok = (w > 0), wr_ok = (w < 55);
#pragma unroll
    for (int kh = 0; kh < 3; ++kh) {
      const float* rp = t0 + kh * 56;
      if (wl_ok) a = fmaf(wreg[kh * 3 + 0], rp[-1], a);
      a = fmaf(wreg[kh * 3 + 1], rp[0], a);
      if (wr_ok) a = fmaf(wreg[kh * 3 + 2], rp[1], a);
    }
    float v = fmaf(a, sc, bb);
    so[(size_t)nl * 384] = v;
    xo[(size_t)nl * 384] = (__bf16)v;
  }
}

// ---------------------------------------------------------------------------
// Final scatter: chunk-local token-major fp32 (mlp2 residual already fused
// in-place) -> NCHW fp32 out. Pure layout copy, both sides coalesced.
// ---------------------------------------------------------------------------
__global__ __launch_bounds__(256)
void winrow_scatter(const float* __restrict__ src, float* __restrict__ outp, int q0)
{
  const int by = blockIdx.y;
  const int q  = q0 + by;
  const int cb = blockIdx.x * 32;
  const int b  = q >> 3, wh = q & 7;
  const int tid = threadIdx.x;
  __shared__ float tile[32 * 393];

  const size_t tl = (size_t)by * 392;
  for (int e = tid; e < 392 * 32; e += 256) {      // ch fast -> 128B read runs
    int nl = e >> 5, ch = e & 31;
    tile[ch * 393 + px_of(nl)] = src[(tl + nl) * 384 + cb + ch];
  }
  __syncthreads();

  float* od = outp + ((size_t)b * C_ + cb) * HW_ + wh * 392;
  for (int e = tid; e < 32 * 392; e += 256) {      // px fast -> 256B write runs
    int ch = e / 392, i = e - ch * 392;
    od[(size_t)ch * HW_ + i] = tile[ch * 393 + i];
  }
}

// ---------------------------------------------------------------------------
extern "C" void kernel_launch(void* const* d_in, const int* in_sizes, int n_in,
                              void* d_out, int out_size, void* d_ws, size_t ws_size,
                              hipStream_t stream)
{
  const float* x      = (const float*)d_in[0];
  const float* ln_g   = (const float*)d_in[1];
  const float* ln_b   = (const float*)d_in[2];
  const float* qkv_w  = (const float*)d_in[3];
  const float* qkv_b  = (const float*)d_in[4];
  const float* proj_w = (const float*)d_in[5];
  const float* proj_b = (const float*)d_in[6];
  const float* btab   = (const float*)d_in[7];
  const float* conv_w = (const float*)d_in[8];
  const float* bn_g   = (const float*)d_in[9];
  const float* bn_b   = (const float*)d_in[10];
  const float* bn_m   = (const float*)d_in[11];
  const float* bn_v   = (const float*)d_in[12];
  const float* w1     = (const float*)d_in[13];
  const float* b1     = (const float*)d_in[14];
  const float* w2     = (const float*)d_in[15];
  const float* b2     = (const float*)d_in[16];
  float* out = (float*)d_out;

  size_t off = 0;
  auto alloc = [&](size_t bytes) -> void* {
    void* p = (char*)d_ws + off;
    off += (bytes + 255) & ~(size_t)255;
    return p;
  };
  // Fixed: 81.4MB (stats 0.8 + weights 3.5 + persistent seqtok 77.1).
  float*  meanb  = (float*)alloc((size_t)NTOK * 4);
  float*  rstdb  = (float*)alloc((size_t)NTOK * 4);
  __bf16* wqb    = (__bf16*)alloc((size_t)1152 * 384 * 2);
  __bf16* wpb    = (__bf16*)alloc((size_t)384  * 384 * 2);
  __bf16* w1b    = (__bf16*)alloc((size_t)1536 * 384 * 2);
  __bf16* w2b    = (__bf16*)alloc((size_t)384  * 1536 * 2);
  __bf16* seqtok = (__bf16*)alloc((size_t)NTOK * 384 * 2);  // x + proj (conv input)

  // Chunk scratch: 5376 B/token (xn 768 + qkv/h 3072 + seq2f 1536).
  int MC = 6272;
  const int opts[5] = {100352, 50176, 25088, 12544, 6272};
  for (int i = 0; i < 5; ++i)
    if (off + (size_t)opts[i] * 5376 + 8192 <= ws_size) { MC = opts[i]; break; }

  __bf16* xn    = (__bf16*)alloc((size_t)MC * 384 * 2);   // LN tokens / attn out / mlp in
  __bf16* qkvb  = (__bf16*)alloc((size_t)MC * 1536 * 2);  // qkv (1152 used) / mlp hidden
  float*  seq2f = (float*)alloc((size_t)MC * 384 * 4);    // dwconv out f32; mlp2 accums in-place

  const int nchunks = NTOK / MC;
  const int wrc = MC / 392;   // window-rows per chunk

  convert_weights<<<6912, 256, 0, stream>>>(qkv_w, proj_w, w1, w2, wqb, wpb, w1b, w2b);
  ln_stats<<<dim3(13, NB_), 256, 0, stream>>>(x, meanb, rstdb);

  for (int ci = 0; ci < nchunks; ++ci) {
    const int q0 = ci * wrc;
    winrow_gather_ln<<<dim3(12, wrc), 256, 0, stream>>>(x, meanb, rstdb, ln_g, ln_b, xn, seqtok, q0);
    gemm_bt<0><<<dim3(9, MC / 128), 256, 0, stream>>>(xn, wqb, qkv_b, qkvb, MC, 1152, 384);
    attn_win<<<dim3(12, MC / 49), 64, 0, stream>>>(qkvb, btab, xn);
    gemm_bt<3><<<dim3(3, MC / 128), 256, 0, stream>>>(xn, wpb, proj_b,
        seqtok + (size_t)q0 * 392 * 384, MC, 384, 384);
  }

  for (int ci = 0; ci < nchunks; ++ci) {
    const int q0 = ci * wrc;
    dwconv_winrow<<<dim3(12, wrc), 256, 0, stream>>>(seqtok, conv_w, bn_g, bn_b, bn_m, bn_v,
                                                     xn, seq2f, q0);
    gemm_bt<1><<<dim3(12, MC / 128), 256, 0, stream>>>(xn, w1b, b1, qkvb, MC, 1536, 384);
    gemm_bt<4><<<dim3(3, MC / 128), 256, 0, stream>>>(qkvb, w2b, b2, seq2f, MC, 384, 1536);
    winrow_scatter<<<dim3(12, wrc), 256, 0, stream>>>(seq2f, out, q0);
  }
}

// Round 3
// 1724.319 us; speedup vs baseline: 1.3888x; 1.3888x over previous
//
#include <hip/hip_runtime.h>
#include <cstdint>
#include <cstddef>

// ---------------------------------------------------------------------------
// TinyViT block (window attention + dwconv/BN + MLP) for MI355X / gfx950.
// Token order: token = win*49 + n, win = ((b*8+wh)*8+ww), n = r*7+c,
// spatial (h,w) = (wh*7+r, ww*7+c). 56 = 8*7 (no padding).
//
// R5 = R4 pipeline + attention spill fix.
//   R4's attn_win used f32x4 q4[8]/o4[8] ext-vector arrays -> VGPR
//   fragmentation -> 256-VGPR cap -> p[49]/q/o spilled to scratch ->
//   933MB HBM traffic & 475us/dispatch (was the whole regression).
//   R5 reverts attention compute to the proven scalar-register form
//   (q[32], p[49], o[32]; broadcast fp32 LDS reads), keeping bf16x8
//   vector staging loads only.
//
// Structure (R4): window-ROW blocking for all layout transforms (both
// sides coalesce); token-major dwconv with halo; proj GEMM accumulates
// shortcut in-place (bf16) into persistent seqtok; mlp2 accumulates
// in-place (fp32) into seq2f; final scatter is a pure coalesced copy.
// ---------------------------------------------------------------------------

typedef __bf16 bf16x8 __attribute__((ext_vector_type(8)));
typedef float  f32x4  __attribute__((ext_vector_type(4)));

#define DEVI __device__ __forceinline__

static constexpr int   C_    = 384;
static constexpr int   HW_   = 3136;      // 56*56
static constexpr int   NB_   = 32;        // batch
static constexpr int   NTOK  = 100352;    // 32*3136
static constexpr float EPS_  = 1e-5f;
static constexpr float ASCAL = 0.17677669529663689f;  // 32^-0.5

DEVI void gld16(const void* g, void* l) {
  __builtin_amdgcn_global_load_lds((__attribute__((address_space(1))) void*)(g),
                                   (__attribute__((address_space(3))) void*)(l),
                                   16, 0, 0);
}

// n_local in [0,392): ww*49 + r*7 + c  ->  px = r*56 + ww*7 + c
DEVI int px_of(int nl) {
  int ww = nl / 49, nn = nl - ww * 49;
  int r  = nn / 7,  c  = nn - r * 7;
  return r * 56 + ww * 7 + c;
}

// ---------------------------------------------------------------------------
// GEMM: C[m,n] = epi( sum_k A[m,k]*Bt[n,k] + bias[n] )
// EPI: 0 = bf16 store
//      1 = bf16 store, exact gelu
//      3 = bf16 IN-PLACE accumulate (outp[m,n] += v, bf16)
//      4 = f32  IN-PLACE accumulate (outp[m,n] += v, fp32)
// ---------------------------------------------------------------------------
template <int EPI>
__global__ __launch_bounds__(256)
void gemm_bt(const __bf16* __restrict__ A, const __bf16* __restrict__ Bt,
             const float* __restrict__ bias, void* __restrict__ outp,
             int M, int N, int K)
{
  __shared__ __align__(16) __bf16 As[128 * 32];
  __shared__ __align__(16) __bf16 Bs[128 * 32];

  const int tid  = threadIdx.x;
  const int lane = tid & 63;
  const int wave = tid >> 6;
  const int quad = lane >> 4;
  const int l16  = lane & 15;
  const int wr   = (wave >> 1) * 64;
  const int wc   = (wave & 1) * 64;
  const size_t m0 = (size_t)blockIdx.y * 128;
  const size_t n0 = (size_t)blockIdx.x * 128;

  const int srow = tid >> 2;
  const int skc  = (tid & 3) * 8;
  const __bf16* ga0 = A  + (m0 + srow) * (size_t)K + skc;
  const __bf16* ga1 = ga0 + (size_t)64 * K;
  const __bf16* gb0 = Bt + (n0 + srow) * (size_t)K + skc;
  const __bf16* gb1 = gb0 + (size_t)64 * K;
  __bf16* la0 = As + tid * 8;
  __bf16* la1 = As + 2048 + tid * 8;
  __bf16* lb0 = Bs + tid * 8;
  __bf16* lb1 = Bs + 2048 + tid * 8;

  f32x4 acc[4][4] = {};

  const int kiters = K >> 5;
  for (int kb = 0; kb < kiters; ++kb) {
    gld16(ga0, la0); gld16(ga1, la1);
    gld16(gb0, lb0); gld16(gb1, lb1);
    ga0 += 32; ga1 += 32; gb0 += 32; gb1 += 32;
    __syncthreads();
    bf16x8 af[4], bfr[4];
#pragma unroll
    for (int i = 0; i < 4; ++i)
      af[i] = *(const bf16x8*)(As + (wr + i * 16 + l16) * 32 + quad * 8);
#pragma unroll
    for (int j = 0; j < 4; ++j)
      bfr[j] = *(const bf16x8*)(Bs + (wc + j * 16 + l16) * 32 + quad * 8);
#pragma unroll
    for (int i = 0; i < 4; ++i)
#pragma unroll
      for (int j = 0; j < 4; ++j)
        acc[i][j] = __builtin_amdgcn_mfma_f32_16x16x32_bf16(af[i], bfr[j], acc[i][j], 0, 0, 0);
    __syncthreads();
  }

  // C/D layout: col = lane&15, row = (lane>>4)*4 + reg   [measured m89/m91]
#pragma unroll
  for (int j = 0; j < 4; ++j) {
    const size_t ng = n0 + wc + j * 16 + l16;
    const float bv = bias[ng];
#pragma unroll
    for (int i = 0; i < 4; ++i) {
      const size_t mg = m0 + wr + i * 16 + quad * 4;
#pragma unroll
      for (int r = 0; r < 4; ++r) {
        float v = acc[i][j][r] + bv;
        const size_t idx = (mg + r) * (size_t)N + ng;
        if (EPI == 1) v = 0.5f * v * (1.0f + erff(v * 0.70710678118654752f));
        if (EPI == 3) {
          __bf16* o = (__bf16*)outp;
          v += (float)o[idx];
          o[idx] = (__bf16)v;
        } else if (EPI == 4) {
          float* o = (float*)outp;
          v += o[idx];
          o[idx] = v;
        } else {
          ((__bf16*)outp)[idx] = (__bf16)v;
        }
      }
    }
  }
}

// ---------------------------------------------------------------------------
// Per-token LayerNorm statistics (x in NCHW, coalesced over hw).
// ---------------------------------------------------------------------------
__global__ __launch_bounds__(256)
void ln_stats(const float* __restrict__ x, float* __restrict__ mean,
              float* __restrict__ rstd)
{
  const int b  = blockIdx.y;
  const int hw = blockIdx.x * 256 + threadIdx.x;
  if (hw >= HW_) return;
  const float* p = x + (size_t)b * (C_ * HW_) + hw;
  float s = 0.f, ss = 0.f;
  for (int c = 0; c < C_; ++c) {
    float v = p[(size_t)c * HW_];
    s += v; ss = fmaf(v, v, ss);
  }
  float mu  = s * (1.0f / C_);
  float var = ss * (1.0f / C_) - mu * mu;
  mean[b * HW_ + hw] = mu;
  rstd[b * HW_ + hw] = rsqrtf(var + EPS_);
}

// ---------------------------------------------------------------------------
// fp32 weight -> bf16 copies (qkv_w, proj_w, w1, w2), one launch.
// ---------------------------------------------------------------------------
__global__ __launch_bounds__(256)
void convert_weights(const float* __restrict__ a, const float* __restrict__ b,
                     const float* __restrict__ c, const float* __restrict__ d,
                     __bf16* __restrict__ oa, __bf16* __restrict__ ob,
                     __bf16* __restrict__ oc, __bf16* __restrict__ od)
{
  int i = blockIdx.x * 256 + threadIdx.x;
  if      (i < 442368)  oa[i] = (__bf16)a[i];
  else if (i < 589824)  ob[i - 442368]  = (__bf16)b[i - 442368];
  else if (i < 1179648) oc[i - 589824]  = (__bf16)c[i - 589824];
  else if (i < 1769472) od[i - 1179648] = (__bf16)d[i - 1179648];
}

// ---------------------------------------------------------------------------
// Window-row gather: NCHW fp32 -> token-major. Emits LN'd bf16 (xn,
// chunk-local) AND raw bf16 tokens (seqtok, GLOBAL index — the proj GEMM
// accumulates the shortcut in-place there).
// ---------------------------------------------------------------------------
__global__ __launch_bounds__(256)
void winrow_gather_ln(const float* __restrict__ x, const float* __restrict__ mean,
                      const float* __restrict__ rstd, const float* __restrict__ gamma,
                      const float* __restrict__ beta, __bf16* __restrict__ xn,
                      __bf16* __restrict__ seqtok, int q0)
{
  const int by = blockIdx.y;
  const int q  = q0 + by;               // global window-row: b*8 + wh
  const int cb = blockIdx.x * 32;
  const int b  = q >> 3, wh = q & 7;
  const int tid = threadIdx.x;
  __shared__ float tile[32 * 393];      // [ch][px], stride 393
  __shared__ float ms[392], rs[392];

  for (int i = tid; i < 392; i += 256) {
    ms[i] = mean[b * HW_ + wh * 392 + i];
    rs[i] = rstd[b * HW_ + wh * 392 + i];
  }
  const float* xs = x + ((size_t)b * C_ + cb) * HW_ + wh * 392;
  for (int e = tid; e < 32 * 392; e += 256) {      // i fast -> coalesced 1KB/wave
    int ch = e / 392, i = e - ch * 392;
    tile[ch * 393 + i] = xs[(size_t)ch * HW_ + i];
  }
  __syncthreads();

  const int ch = tid & 31;
  const float g  = gamma[cb + ch];
  const float bt = beta[cb + ch];
  __bf16* xo = xn     + ((size_t)by * 392) * 384 + cb + ch;   // chunk-local
  __bf16* sr = seqtok + ((size_t)q  * 392) * 384 + cb + ch;   // global
  for (int n = tid >> 5; n < 392; n += 8) {
    int px = px_of(n);
    float v = tile[ch * 393 + px];
    sr[(size_t)n * 384] = (__bf16)v;
    xo[(size_t)n * 384] = (__bf16)((v - ms[px]) * rs[px] * g + bt);
  }
}

// ---------------------------------------------------------------------------
// Window attention, one wave per (window, head). K,V staged fp32 in LDS
// (bf16x8 vector staging loads). Compute kept fully SCALAR (q[32], p[49],
// o[32]) — the f32x4 formulation fragmented the register file, hit the
// 256-VGPR cap and spilled p[] to scratch (933MB HBM/dispatch, R4).
// ---------------------------------------------------------------------------
__global__ __launch_bounds__(64)
void attn_win(const __bf16* __restrict__ qkv, const float* __restrict__ btab,
              __bf16* __restrict__ attn_out)
{
  const int head = blockIdx.x;
  const int wl   = blockIdx.y;
  const int lane = threadIdx.x;

  __shared__ __align__(16) float ks[49 * 32];
  __shared__ __align__(16) float vs[49 * 32];
  __shared__ float bs[169];

  const __bf16* base = qkv + (size_t)wl * (49 * 1152) + head * 32;
  for (int e = lane; e < 196; e += 64) {           // 49 tokens x 4 groups of 8
    int n = e >> 2, g4 = e & 3;
    const __bf16* rp = base + (size_t)n * 1152;
    bf16x8 kk = *(const bf16x8*)(rp + 384 + g4 * 8);
    bf16x8 vv = *(const bf16x8*)(rp + 768 + g4 * 8);
    float* kd = ks + n * 32 + g4 * 8;
    float* vd = vs + n * 32 + g4 * 8;
#pragma unroll
    for (int u = 0; u < 8; ++u) { kd[u] = (float)kk[u]; vd[u] = (float)vv[u]; }
  }
  for (int e = lane; e < 169; e += 64) bs[e] = btab[e * 12 + head];
  __syncthreads();

  if (lane >= 49) return;
  const int ri = lane / 7, ci = lane % 7;
  float q[32];
  const __bf16* qp = base + (size_t)lane * 1152;
#pragma unroll
  for (int d = 0; d < 32; ++d) q[d] = (float)qp[d] * ASCAL;

  float p[49];
  float mx = -1e30f;
#pragma unroll
  for (int j = 0; j < 49; ++j) {
    float s = bs[(ri - j / 7 + 6) * 13 + (ci - j % 7 + 6)];
    const float* kj = ks + j * 32;
#pragma unroll
    for (int d = 0; d < 32; ++d) s = fmaf(q[d], kj[d], s);
    p[j] = s;
    mx = fmaxf(mx, s);
  }
  float sum = 0.f;
#pragma unroll
  for (int j = 0; j < 49; ++j) { float e = __expf(p[j] - mx); p[j] = e; sum += e; }
  const float inv = 1.0f / sum;

  float o[32];
#pragma unroll
  for (int d = 0; d < 32; ++d) o[d] = 0.f;
#pragma unroll
  for (int j = 0; j < 49; ++j) {
    const float pj = p[j];
    const float* vj = vs + j * 32;
#pragma unroll
    for (int d = 0; d < 32; ++d) o[d] = fmaf(pj, vj[d], o[d]);
  }
  __bf16* op = attn_out + ((size_t)wl * 49 + lane) * 384 + head * 32;
#pragma unroll
  for (int g = 0; g < 4; ++g) {
    bf16x8 t;
#pragma unroll
    for (int u = 0; u < 8; ++u) t[u] = (__bf16)(o[g * 8 + u] * inv);
    *(bf16x8*)(op + g * 8) = t;
  }
}

// ---------------------------------------------------------------------------
// Depthwise 3x3 conv (pad 1) + inference BN, fully token-major.
// Block = (channel-chunk of 32, window-row). Stages rows [7wh-1, 7wh+7]
// (halo from window-rows q-1/q+1 of GLOBAL seqtok; zeros at image edges)
// in LDS fp32, 9-tap, writes bf16 tokens (MLP input, chunk-local) + fp32
// tokens (seq2 residual, chunk-local). LDS 32*505*4 = 64,640B.
// ---------------------------------------------------------------------------
__global__ __launch_bounds__(256)
void dwconv_winrow(const __bf16* __restrict__ seqtok, const float* __restrict__ cw,
                   const float* __restrict__ g, const float* __restrict__ bta,
                   const float* __restrict__ mn, const float* __restrict__ vr,
                   __bf16* __restrict__ xn, float* __restrict__ seq2f, int q0)
{
  const int by = blockIdx.y;
  const int q  = q0 + by;               // global window-row
  const int cb = blockIdx.x * 32;
  const int wh = q & 7;
  const int tid = threadIdx.x;
  __shared__ float tile[32 * 505];      // [ch][9*56], stride 505

  const size_t tg = (size_t)q  * 392;   // global token base
  const size_t tl = (size_t)by * 392;   // chunk-local token base

  // main slab: spatial rows 7wh..7wh+6 -> tile rows 1..7
  for (int e = tid; e < 392 * 4; e += 256) {       // token x 4 groups of 8ch
    int nl = e >> 2, gg = e & 3;
    bf16x8 t = *(const bf16x8*)(seqtok + (tg + nl) * 384 + cb + gg * 8);
    int px = px_of(nl) + 56;
#pragma unroll
    for (int u = 0; u < 8; ++u) tile[(gg * 8 + u) * 505 + px] = (float)t[u];
  }
  // halo rows 0 and 8
  for (int e = tid; e < 224; e += 256) {           // 56 cols x 4 groups
    int w = e >> 2, gg = e & 3;
    int ww = w / 7, c = w - ww * 7;
    float tv[8], bv[8];
    if (wh > 0) {
      bf16x8 t = *(const bf16x8*)(seqtok + ((size_t)(q - 1) * 392 + ww * 49 + 42 + c) * 384 + cb + gg * 8);
#pragma unroll
      for (int u = 0; u < 8; ++u) tv[u] = (float)t[u];
    } else {
#pragma unroll
      for (int u = 0; u < 8; ++u) tv[u] = 0.f;
    }
    if (wh < 7) {
      bf16x8 t = *(const bf16x8*)(seqtok + ((size_t)(q + 1) * 392 + ww * 49 + c) * 384 + cb + gg * 8);
#pragma unroll
      for (int u = 0; u < 8; ++u) bv[u] = (float)t[u];
    } else {
#pragma unroll
      for (int u = 0; u < 8; ++u) bv[u] = 0.f;
    }
#pragma unroll
    for (int u = 0; u < 8; ++u) {
      tile[(gg * 8 + u) * 505 + w]       = tv[u];
      tile[(gg * 8 + u) * 505 + 448 + w] = bv[u];
    }
  }
  __syncthreads();

  const int ch = tid & 31;
  float wreg[9];
#pragma unroll
  for (int k = 0; k < 9; ++k) wreg[k] = cw[(cb + ch) * 9 + k];
  const float sc = g[cb + ch] * rsqrtf(vr[cb + ch] + EPS_);
  const float bb = bta[cb + ch] - mn[cb + ch] * sc;

  __bf16* xo = xn    + tl * 384 + cb + ch;
  float*  so = seq2f + tl * 384 + cb + ch;
  for (int nl = tid >> 5; nl < 392; nl += 8) {
    int ww = nl / 49, nn = nl - ww * 49;
    int rr = nn / 7,  cc = nn - rr * 7;
    int w  = ww * 7 + cc;
    const float* t0 = tile + ch * 505 + rr * 56 + w;
    float a = 0.f;
    const bool wl_ok = (w > 0), wr_ok = (w < 55);
#pragma unroll
    for (int kh = 0; kh < 3; ++kh) {
      const float* rp = t0 + kh * 56;
      if (wl_ok) a = fmaf(wreg[kh * 3 + 0], rp[-1], a);
      a = fmaf(wreg[kh * 3 + 1], rp[0], a);
      if (wr_ok) a = fmaf(wreg[kh * 3 + 2], rp[1], a);
    }
    float v = fmaf(a, sc, bb);
    so[(size_t)nl * 384] = v;
    xo[(size_t)nl * 384] = (__bf16)v;
  }
}

// ---------------------------------------------------------------------------
// Final scatter: chunk-local token-major fp32 (mlp2 residual already fused
// in-place) -> NCHW fp32 out. Pure layout copy, both sides coalesced.
// ---------------------------------------------------------------------------
__global__ __launch_bounds__(256)
void winrow_scatter(const float* __restrict__ src, float* __restrict__ outp, int q0)
{
  const int by = blockIdx.y;
  const int q  = q0 + by;
  const int cb = blockIdx.x * 32;
  const int b  = q >> 3, wh = q & 7;
  const int tid = threadIdx.x;
  __shared__ float tile[32 * 393];

  const size_t tl = (size_t)by * 392;
  for (int e = tid; e < 392 * 32; e += 256) {      // ch fast -> 128B read runs
    int nl = e >> 5, ch = e & 31;
    tile[ch * 393 + px_of(nl)] = src[(tl + nl) * 384 + cb + ch];
  }
  __syncthreads();

  float* od = outp + ((size_t)b * C_ + cb) * HW_ + wh * 392;
  for (int e = tid; e < 32 * 392; e += 256) {      // px fast -> 256B write runs
    int ch = e / 392, i = e - ch * 392;
    od[(size_t)ch * HW_ + i] = tile[ch * 393 + i];
  }
}

// ---------------------------------------------------------------------------
extern "C" void kernel_launch(void* const* d_in, const int* in_sizes, int n_in,
                              void* d_out, int out_size, void* d_ws, size_t ws_size,
                              hipStream_t stream)
{
  const float* x      = (const float*)d_in[0];
  const float* ln_g   = (const float*)d_in[1];
  const float* ln_b   = (const float*)d_in[2];
  const float* qkv_w  = (const float*)d_in[3];
  const float* qkv_b  = (const float*)d_in[4];
  const float* proj_w = (const float*)d_in[5];
  const float* proj_b = (const float*)d_in[6];
  const float* btab   = (const float*)d_in[7];
  const float* conv_w = (const float*)d_in[8];
  const float* bn_g   = (const float*)d_in[9];
  const float* bn_b   = (const float*)d_in[10];
  const float* bn_m   = (const float*)d_in[11];
  const float* bn_v   = (const float*)d_in[12];
  const float* w1     = (const float*)d_in[13];
  const float* b1     = (const float*)d_in[14];
  const float* w2     = (const float*)d_in[15];
  const float* b2     = (const float*)d_in[16];
  float* out = (float*)d_out;

  size_t off = 0;
  auto alloc = [&](size_t bytes) -> void* {
    void* p = (char*)d_ws + off;
    off += (bytes + 255) & ~(size_t)255;
    return p;
  };
  // Fixed: 81.4MB (stats 0.8 + weights 3.5 + persistent seqtok 77.1).
  float*  meanb  = (float*)alloc((size_t)NTOK * 4);
  float*  rstdb  = (float*)alloc((size_t)NTOK * 4);
  __bf16* wqb    = (__bf16*)alloc((size_t)1152 * 384 * 2);
  __bf16* wpb    = (__bf16*)alloc((size_t)384  * 384 * 2);
  __bf16* w1b    = (__bf16*)alloc((size_t)1536 * 384 * 2);
  __bf16* w2b    = (__bf16*)alloc((size_t)384  * 1536 * 2);
  __bf16* seqtok = (__bf16*)alloc((size_t)NTOK * 384 * 2);  // x + proj (conv input)

  // Chunk scratch: 5376 B/token (xn 768 + qkv/h 3072 + seq2f 1536).
  int MC = 6272;
  const int opts[5] = {100352, 50176, 25088, 12544, 6272};
  for (int i = 0; i < 5; ++i)
    if (off + (size_t)opts[i] * 5376 + 8192 <= ws_size) { MC = opts[i]; break; }

  __bf16* xn    = (__bf16*)alloc((size_t)MC * 384 * 2);   // LN tokens / attn out / mlp in
  __bf16* qkvb  = (__bf16*)alloc((size_t)MC * 1536 * 2);  // qkv (1152 used) / mlp hidden
  float*  seq2f = (float*)alloc((size_t)MC * 384 * 4);    // dwconv out f32; mlp2 accums in-place

  const int nchunks = NTOK / MC;
  const int wrc = MC / 392;   // window-rows per chunk

  convert_weights<<<6912, 256, 0, stream>>>(qkv_w, proj_w, w1, w2, wqb, wpb, w1b, w2b);
  ln_stats<<<dim3(13, NB_), 256, 0, stream>>>(x, meanb, rstdb);

  for (int ci = 0; ci < nchunks; ++ci) {
    const int q0 = ci * wrc;
    winrow_gather_ln<<<dim3(12, wrc), 256, 0, stream>>>(x, meanb, rstdb, ln_g, ln_b, xn, seqtok, q0);
    gemm_bt<0><<<dim3(9, MC / 128), 256, 0, stream>>>(xn, wqb, qkv_b, qkvb, MC, 1152, 384);
    attn_win<<<dim3(12, MC / 49), 64, 0, stream>>>(qkvb, btab, xn);
    gemm_bt<3><<<dim3(3, MC / 128), 256, 0, stream>>>(xn, wpb, proj_b,
        seqtok + (size_t)q0 * 392 * 384, MC, 384, 384);
  }

  for (int ci = 0; ci < nchunks; ++ci) {
    const int q0 = ci * wrc;
    dwconv_winrow<<<dim3(12, wrc), 256, 0, stream>>>(seqtok, conv_w, bn_g, bn_b, bn_m, bn_v,
                                                     xn, seq2f, q0);
    gemm_bt<1><<<dim3(12, MC / 128), 256, 0, stream>>>(xn, w1b, b1, qkvb, MC, 1536, 384);
    gemm_bt<4><<<dim3(3, MC / 128), 256, 0, stream>>>(qkvb, w2b, b2, seq2f, MC, 384, 1536);
    winrow_scatter<<<dim3(12, wrc), 256, 0, stream>>>(seq2f, out, q0);
  }
}

// Round 4
// 1721.182 us; speedup vs baseline: 1.3913x; 1.0018x over previous
//
#include <hip/hip_runtime.h>
#include <cstdint>
#include <cstddef>

// ---------------------------------------------------------------------------
// TinyViT block (window attention + dwconv/BN + MLP) for MI355X / gfx950.
// Token order: token = win*49 + n, win = ((b*8+wh)*8+ww), n = r*7+c,
// spatial (h,w) = (wh*7+r, ww*7+c). 56 = 8*7 (no padding).
//
// R6 = R5 + double-buffered GEMM K-loop (T3 2-phase).
//   R5's gemm: stage -> barrier(vmcnt0 drain: FULL ~900cy HBM latency
//   exposed per K-step) -> compute -> barrier. Measured 1750 cyc/K-step
//   vs ~600 of real work (MfmaUtil 13%, nothing saturated = latency).
//   R6: LDS double-buffer (BK=32, 32KB), ONE barrier per K-step, next
//   tile's global_load_lds issued BEFORE current tile's ds_read+MFMA so
//   the load flight time hides under compute; barrier drain pays only
//   the residual.
//
// Structure (R4/R5): window-ROW blocking for all layout transforms (both
// sides coalesce); token-major dwconv with halo; proj GEMM accumulates
// shortcut in-place (bf16) into persistent seqtok; mlp2 accumulates
// in-place (fp32) into seq2f; final scatter is a pure coalesced copy.
// attn compute stays SCALAR (R4's f32x4 arrays spilled -> 933MB scratch
// traffic).
// ---------------------------------------------------------------------------

typedef __bf16 bf16x8 __attribute__((ext_vector_type(8)));
typedef float  f32x4  __attribute__((ext_vector_type(4)));

#define DEVI __device__ __forceinline__

static constexpr int   C_    = 384;
static constexpr int   HW_   = 3136;      // 56*56
static constexpr int   NB_   = 32;        // batch
static constexpr int   NTOK  = 100352;    // 32*3136
static constexpr float EPS_  = 1e-5f;
static constexpr float ASCAL = 0.17677669529663689f;  // 32^-0.5

DEVI void gld16(const void* g, void* l) {
  __builtin_amdgcn_global_load_lds((__attribute__((address_space(1))) void*)(g),
                                   (__attribute__((address_space(3))) void*)(l),
                                   16, 0, 0);
}

// n_local in [0,392): ww*49 + r*7 + c  ->  px = r*56 + ww*7 + c
DEVI int px_of(int nl) {
  int ww = nl / 49, nn = nl - ww * 49;
  int r  = nn / 7,  c  = nn - r * 7;
  return r * 56 + ww * 7 + c;
}

// ---------------------------------------------------------------------------
// GEMM: C[m,n] = epi( sum_k A[m,k]*Bt[n,k] + bias[n] )
// EPI: 0 = bf16 store
//      1 = bf16 store, exact gelu
//      3 = bf16 IN-PLACE accumulate (outp[m,n] += v, bf16)
//      4 = f32  IN-PLACE accumulate (outp[m,n] += v, fp32)
// Double-buffered: stage(kb+1) issued before compute(kb); one barrier/iter.
// ---------------------------------------------------------------------------
template <int EPI>
__global__ __launch_bounds__(256)
void gemm_bt(const __bf16* __restrict__ A, const __bf16* __restrict__ Bt,
             const float* __restrict__ bias, void* __restrict__ outp,
             int M, int N, int K)
{
  __shared__ __align__(16) __bf16 As[2][128 * 32];
  __shared__ __align__(16) __bf16 Bs[2][128 * 32];

  const int tid  = threadIdx.x;
  const int lane = tid & 63;
  const int wave = tid >> 6;
  const int quad = lane >> 4;
  const int l16  = lane & 15;
  const int wr   = (wave >> 1) * 64;
  const int wc   = (wave & 1) * 64;
  const size_t m0 = (size_t)blockIdx.y * 128;
  const size_t n0 = (size_t)blockIdx.x * 128;

  const int srow = tid >> 2;
  const int skc  = (tid & 3) * 8;
  const __bf16* ga0 = A  + (m0 + srow) * (size_t)K + skc;
  const __bf16* ga1 = ga0 + (size_t)64 * K;
  const __bf16* gb0 = Bt + (n0 + srow) * (size_t)K + skc;
  const __bf16* gb1 = gb0 + (size_t)64 * K;

  f32x4 acc[4][4] = {};

  const int kiters = K >> 5;

  // prologue: stage tile 0 into buffer 0
  gld16(ga0, As[0] + tid * 8);
  gld16(ga1, As[0] + 2048 + tid * 8);
  gld16(gb0, Bs[0] + tid * 8);
  gld16(gb1, Bs[0] + 2048 + tid * 8);
  ga0 += 32; ga1 += 32; gb0 += 32; gb1 += 32;
  __syncthreads();   // drains vmcnt(0): tile 0 resident

  for (int kb = 0; kb < kiters; ++kb) {
    const int cur = kb & 1;
    // issue next tile's loads FIRST (latency hides under compute below)
    if (kb + 1 < kiters) {
      const int nxt = cur ^ 1;
      gld16(ga0, As[nxt] + tid * 8);
      gld16(ga1, As[nxt] + 2048 + tid * 8);
      gld16(gb0, Bs[nxt] + tid * 8);
      gld16(gb1, Bs[nxt] + 2048 + tid * 8);
      ga0 += 32; ga1 += 32; gb0 += 32; gb1 += 32;
    }
    // compute current tile (MFMA waits only on lgkmcnt, not vmcnt)
    bf16x8 af[4], bfr[4];
#pragma unroll
    for (int i = 0; i < 4; ++i)
      af[i] = *(const bf16x8*)(As[cur] + (wr + i * 16 + l16) * 32 + quad * 8);
#pragma unroll
    for (int j = 0; j < 4; ++j)
      bfr[j] = *(const bf16x8*)(Bs[cur] + (wc + j * 16 + l16) * 32 + quad * 8);
#pragma unroll
    for (int i = 0; i < 4; ++i)
#pragma unroll
      for (int j = 0; j < 4; ++j)
        acc[i][j] = __builtin_amdgcn_mfma_f32_16x16x32_bf16(af[i], bfr[j], acc[i][j], 0, 0, 0);
    // one barrier per iter: drains residual vmcnt (next tile) + guards
    // buffer reuse (stage at kb+1 overwrites cur^1^1 = the buffer read here
    // two iterations later; all reads of cur are done past this barrier).
    __syncthreads();
  }

  // C/D layout: col = lane&15, row = (lane>>4)*4 + reg   [measured m89/m91]
#pragma unroll
  for (int j = 0; j < 4; ++j) {
    const size_t ng = n0 + wc + j * 16 + l16;
    const float bv = bias[ng];
#pragma unroll
    for (int i = 0; i < 4; ++i) {
      const size_t mg = m0 + wr + i * 16 + quad * 4;
#pragma unroll
      for (int r = 0; r < 4; ++r) {
        float v = acc[i][j][r] + bv;
        const size_t idx = (mg + r) * (size_t)N + ng;
        if (EPI == 1) v = 0.5f * v * (1.0f + erff(v * 0.70710678118654752f));
        if (EPI == 3) {
          __bf16* o = (__bf16*)outp;
          v += (float)o[idx];
          o[idx] = (__bf16)v;
        } else if (EPI == 4) {
          float* o = (float*)outp;
          v += o[idx];
          o[idx] = v;
        } else {
          ((__bf16*)outp)[idx] = (__bf16)v;
        }
      }
    }
  }
}

// ---------------------------------------------------------------------------
// Per-token LayerNorm statistics (x in NCHW, coalesced over hw).
// ---------------------------------------------------------------------------
__global__ __launch_bounds__(256)
void ln_stats(const float* __restrict__ x, float* __restrict__ mean,
              float* __restrict__ rstd)
{
  const int b  = blockIdx.y;
  const int hw = blockIdx.x * 256 + threadIdx.x;
  if (hw >= HW_) return;
  const float* p = x + (size_t)b * (C_ * HW_) + hw;
  float s = 0.f, ss = 0.f;
  for (int c = 0; c < C_; ++c) {
    float v = p[(size_t)c * HW_];
    s += v; ss = fmaf(v, v, ss);
  }
  float mu  = s * (1.0f / C_);
  float var = ss * (1.0f / C_) - mu * mu;
  mean[b * HW_ + hw] = mu;
  rstd[b * HW_ + hw] = rsqrtf(var + EPS_);
}

// ---------------------------------------------------------------------------
// fp32 weight -> bf16 copies (qkv_w, proj_w, w1, w2), one launch.
// ---------------------------------------------------------------------------
__global__ __launch_bounds__(256)
void convert_weights(const float* __restrict__ a, const float* __restrict__ b,
                     const float* __restrict__ c, const float* __restrict__ d,
                     __bf16* __restrict__ oa, __bf16* __restrict__ ob,
                     __bf16* __restrict__ oc, __bf16* __restrict__ od)
{
  int i = blockIdx.x * 256 + threadIdx.x;
  if      (i < 442368)  oa[i] = (__bf16)a[i];
  else if (i < 589824)  ob[i - 442368]  = (__bf16)b[i - 442368];
  else if (i < 1179648) oc[i - 589824]  = (__bf16)c[i - 589824];
  else if (i < 1769472) od[i - 1179648] = (__bf16)d[i - 1179648];
}

// ---------------------------------------------------------------------------
// Window-row gather: NCHW fp32 -> token-major. Emits LN'd bf16 (xn,
// chunk-local) AND raw bf16 tokens (seqtok, GLOBAL index — the proj GEMM
// accumulates the shortcut in-place there).
// ---------------------------------------------------------------------------
__global__ __launch_bounds__(256)
void winrow_gather_ln(const float* __restrict__ x, const float* __restrict__ mean,
                      const float* __restrict__ rstd, const float* __restrict__ gamma,
                      const float* __restrict__ beta, __bf16* __restrict__ xn,
                      __bf16* __restrict__ seqtok, int q0)
{
  const int by = blockIdx.y;
  const int q  = q0 + by;               // global window-row: b*8 + wh
  const int cb = blockIdx.x * 32;
  const int b  = q >> 3, wh = q & 7;
  const int tid = threadIdx.x;
  __shared__ float tile[32 * 393];      // [ch][px], stride 393
  __shared__ float ms[392], rs[392];

  for (int i = tid; i < 392; i += 256) {
    ms[i] = mean[b * HW_ + wh * 392 + i];
    rs[i] = rstd[b * HW_ + wh * 392 + i];
  }
  const float* xs = x + ((size_t)b * C_ + cb) * HW_ + wh * 392;
  for (int e = tid; e < 32 * 392; e += 256) {      // i fast -> coalesced 1KB/wave
    int ch = e / 392, i = e - ch * 392;
    tile[ch * 393 + i] = xs[(size_t)ch * HW_ + i];
  }
  __syncthreads();

  const int ch = tid & 31;
  const float g  = gamma[cb + ch];
  const float bt = beta[cb + ch];
  __bf16* xo = xn     + ((size_t)by * 392) * 384 + cb + ch;   // chunk-local
  __bf16* sr = seqtok + ((size_t)q  * 392) * 384 + cb + ch;   // global
  for (int n = tid >> 5; n < 392; n += 8) {
    int px = px_of(n);
    float v = tile[ch * 393 + px];
    sr[(size_t)n * 384] = (__bf16)v;
    xo[(size_t)n * 384] = (__bf16)((v - ms[px]) * rs[px] * g + bt);
  }
}

// ---------------------------------------------------------------------------
// Window attention, one wave per (window, head). K,V staged fp32 in LDS
// (bf16x8 vector staging loads). Compute fully SCALAR (q[32], p[49],
// o[32]) — vector-register formulation spills (R4: 933MB/dispatch).
// ---------------------------------------------------------------------------
__global__ __launch_bounds__(64)
void attn_win(const __bf16* __restrict__ qkv, const float* __restrict__ btab,
              __bf16* __restrict__ attn_out)
{
  const int head = blockIdx.x;
  const int wl   = blockIdx.y;
  const int lane = threadIdx.x;

  __shared__ __align__(16) float ks[49 * 32];
  __shared__ __align__(16) float vs[49 * 32];
  __shared__ float bs[169];

  const __bf16* base = qkv + (size_t)wl * (49 * 1152) + head * 32;
  for (int e = lane; e < 196; e += 64) {           // 49 tokens x 4 groups of 8
    int n = e >> 2, g4 = e & 3;
    const __bf16* rp = base + (size_t)n * 1152;
    bf16x8 kk = *(const bf16x8*)(rp + 384 + g4 * 8);
    bf16x8 vv = *(const bf16x8*)(rp + 768 + g4 * 8);
    float* kd = ks + n * 32 + g4 * 8;
    float* vd = vs + n * 32 + g4 * 8;
#pragma unroll
    for (int u = 0; u < 8; ++u) { kd[u] = (float)kk[u]; vd[u] = (float)vv[u]; }
  }
  for (int e = lane; e < 169; e += 64) bs[e] = btab[e * 12 + head];
  __syncthreads();

  if (lane >= 49) return;
  const int ri = lane / 7, ci = lane % 7;
  float q[32];
  const __bf16* qp = base + (size_t)lane * 1152;
#pragma unroll
  for (int d = 0; d < 32; ++d) q[d] = (float)qp[d] * ASCAL;

  float p[49];
  float mx = -1e30f;
#pragma unroll
  for (int j = 0; j < 49; ++j) {
    float s = bs[(ri - j / 7 + 6) * 13 + (ci - j % 7 + 6)];
    const float* kj = ks + j * 32;
#pragma unroll
    for (int d = 0; d < 32; ++d) s = fmaf(q[d], kj[d], s);
    p[j] = s;
    mx = fmaxf(mx, s);
  }
  float sum = 0.f;
#pragma unroll
  for (int j = 0; j < 49; ++j) { float e = __expf(p[j] - mx); p[j] = e; sum += e; }
  const float inv = 1.0f / sum;

  float o[32];
#pragma unroll
  for (int d = 0; d < 32; ++d) o[d] = 0.f;
#pragma unroll
  for (int j = 0; j < 49; ++j) {
    const float pj = p[j];
    const float* vj = vs + j * 32;
#pragma unroll
    for (int d = 0; d < 32; ++d) o[d] = fmaf(pj, vj[d], o[d]);
  }
  __bf16* op = attn_out + ((size_t)wl * 49 + lane) * 384 + head * 32;
#pragma unroll
  for (int g = 0; g < 4; ++g) {
    bf16x8 t;
#pragma unroll
    for (int u = 0; u < 8; ++u) t[u] = (__bf16)(o[g * 8 + u] * inv);
    *(bf16x8*)(op + g * 8) = t;
  }
}

// ---------------------------------------------------------------------------
// Depthwise 3x3 conv (pad 1) + inference BN, fully token-major.
// Block = (channel-chunk of 32, window-row). Stages rows [7wh-1, 7wh+7]
// (halo from window-rows q-1/q+1 of GLOBAL seqtok; zeros at image edges)
// in LDS fp32, 9-tap, writes bf16 tokens (MLP input, chunk-local) + fp32
// tokens (seq2 residual, chunk-local). LDS 32*505*4 = 64,640B.
// ---------------------------------------------------------------------------
__global__ __launch_bounds__(256)
void dwconv_winrow(const __bf16* __restrict__ seqtok, const float* __restrict__ cw,
                   const float* __restrict__ g, const float* __restrict__ bta,
                   const float* __restrict__ mn, const float* __restrict__ vr,
                   __bf16* __restrict__ xn, float* __restrict__ seq2f, int q0)
{
  const int by = blockIdx.y;
  const int q  = q0 + by;               // global window-row
  const int cb = blockIdx.x * 32;
  const int wh = q & 7;
  const int tid = threadIdx.x;
  __shared__ float tile[32 * 505];      // [ch][9*56], stride 505

  const size_t tg = (size_t)q  * 392;   // global token base
  const size_t tl = (size_t)by * 392;   // chunk-local token base

  // main slab: spatial rows 7wh..7wh+6 -> tile rows 1..7
  for (int e = tid; e < 392 * 4; e += 256) {       // token x 4 groups of 8ch
    int nl = e >> 2, gg = e & 3;
    bf16x8 t = *(const bf16x8*)(seqtok + (tg + nl) * 384 + cb + gg * 8);
    int px = px_of(nl) + 56;
#pragma unroll
    for (int u = 0; u < 8; ++u) tile[(gg * 8 + u) * 505 + px] = (float)t[u];
  }
  // halo rows 0 and 8
  for (int e = tid; e < 224; e += 256) {           // 56 cols x 4 groups
    int w = e >> 2, gg = e & 3;
    int ww = w / 7, c = w - ww * 7;
    float tv[8], bv[8];
    if (wh > 0) {
      bf16x8 t = *(const bf16x8*)(seqtok + ((size_t)(q - 1) * 392 + ww * 49 + 42 + c) * 384 + cb + gg * 8);
#pragma unroll
      for (int u = 0; u < 8; ++u) tv[u] = (float)t[u];
    } else {
#pragma unroll
      for (int u = 0; u < 8; ++u) tv[u] = 0.f;
    }
    if (wh < 7) {
      bf16x8 t = *(const bf16x8*)(seqtok + ((size_t)(q + 1) * 392 + ww * 49 + c) * 384 + cb + gg * 8);
#pragma unroll
      for (int u = 0; u < 8; ++u) bv[u] = (float)t[u];
    } else {
#pragma unroll
      for (int u = 0; u < 8; ++u) bv[u] = 0.f;
    }
#pragma unroll
    for (int u = 0; u < 8; ++u) {
      tile[(gg * 8 + u) * 505 + w]       = tv[u];
      tile[(gg * 8 + u) * 505 + 448 + w] = bv[u];
    }
  }
  __syncthreads();

  const int ch = tid & 31;
  float wreg[9];
#pragma unroll
  for (int k = 0; k < 9; ++k) wreg[k] = cw[(cb + ch) * 9 + k];
  const float sc = g[cb + ch] * rsqrtf(vr[cb + ch] + EPS_);
  const float bb = bta[cb + ch] - mn[cb + ch] * sc;

  __bf16* xo = xn    + tl * 384 + cb + ch;
  float*  so = seq2f + tl * 384 + cb + ch;
  for (int nl = tid >> 5; nl < 392; nl += 8) {
    int ww = nl / 49, nn = nl - ww * 49;
    int rr = nn / 7,  cc = nn - rr * 7;
    int w  = ww * 7 + cc;
    const float* t0 = tile + ch * 505 + rr * 56 + w;
    float a = 0.f;
    const bool wl_ok = (w > 0), wr_ok = (w < 55);
#pragma unroll
    for (int kh = 0; kh < 3; ++kh) {
      const float* rp = t0 + kh * 56;
      if (wl_ok) a = fmaf(wreg[kh * 3 + 0], rp[-1], a);
      a = fmaf(wreg[kh * 3 + 1], rp[0], a);
      if (wr_ok) a = fmaf(wreg[kh * 3 + 2], rp[1], a);
    }
    float v = fmaf(a, sc, bb);
    so[(size_t)nl * 384] = v;
    xo[(size_t)nl * 384] = (__bf16)v;
  }
}

// ---------------------------------------------------------------------------
// Final scatter: chunk-local token-major fp32 (mlp2 residual already fused
// in-place) -> NCHW fp32 out. Pure layout copy, both sides coalesced.
// ---------------------------------------------------------------------------
__global__ __launch_bounds__(256)
void winrow_scatter(const float* __restrict__ src, float* __restrict__ outp, int q0)
{
  const int by = blockIdx.y;
  const int q  = q0 + by;
  const int cb = blockIdx.x * 32;
  const int b  = q >> 3, wh = q & 7;
  const int tid = threadIdx.x;
  __shared__ float tile[32 * 393];

  const size_t tl = (size_t)by * 392;
  for (int e = tid; e < 392 * 32; e += 256) {      // ch fast -> 128B read runs
    int nl = e >> 5, ch = e & 31;
    tile[ch * 393 + px_of(nl)] = src[(tl + nl) * 384 + cb + ch];
  }
  __syncthreads();

  float* od = outp + ((size_t)b * C_ + cb) * HW_ + wh * 392;
  for (int e = tid; e < 32 * 392; e += 256) {      // px fast -> 256B write runs
    int ch = e / 392, i = e - ch * 392;
    od[(size_t)ch * HW_ + i] = tile[ch * 393 + i];
  }
}

// ---------------------------------------------------------------------------
extern "C" void kernel_launch(void* const* d_in, const int* in_sizes, int n_in,
                              void* d_out, int out_size, void* d_ws, size_t ws_size,
                              hipStream_t stream)
{
  const float* x      = (const float*)d_in[0];
  const float* ln_g   = (const float*)d_in[1];
  const float* ln_b   = (const float*)d_in[2];
  const float* qkv_w  = (const float*)d_in[3];
  const float* qkv_b  = (const float*)d_in[4];
  const float* proj_w = (const float*)d_in[5];
  const float* proj_b = (const float*)d_in[6];
  const float* btab   = (const float*)d_in[7];
  const float* conv_w = (const float*)d_in[8];
  const float* bn_g   = (const float*)d_in[9];
  const float* bn_b   = (const float*)d_in[10];
  const float* bn_m   = (const float*)d_in[11];
  const float* bn_v   = (const float*)d_in[12];
  const float* w1     = (const float*)d_in[13];
  const float* b1     = (const float*)d_in[14];
  const float* w2     = (const float*)d_in[15];
  const float* b2     = (const float*)d_in[16];
  float* out = (float*)d_out;

  size_t off = 0;
  auto alloc = [&](size_t bytes) -> void* {
    void* p = (char*)d_ws + off;
    off += (bytes + 255) & ~(size_t)255;
    return p;
  };
  // Fixed: 81.4MB (stats 0.8 + weights 3.5 + persistent seqtok 77.1).
  float*  meanb  = (float*)alloc((size_t)NTOK * 4);
  float*  rstdb  = (float*)alloc((size_t)NTOK * 4);
  __bf16* wqb    = (__bf16*)alloc((size_t)1152 * 384 * 2);
  __bf16* wpb    = (__bf16*)alloc((size_t)384  * 384 * 2);
  __bf16* w1b    = (__bf16*)alloc((size_t)1536 * 384 * 2);
  __bf16* w2b    = (__bf16*)alloc((size_t)384  * 1536 * 2);
  __bf16* seqtok = (__bf16*)alloc((size_t)NTOK * 384 * 2);  // x + proj (conv input)

  // Chunk scratch: 5376 B/token (xn 768 + qkv/h 3072 + seq2f 1536).
  int MC = 6272;
  const int opts[5] = {100352, 50176, 25088, 12544, 6272};
  for (int i = 0; i < 5; ++i)
    if (off + (size_t)opts[i] * 5376 + 8192 <= ws_size) { MC = opts[i]; break; }

  __bf16* xn    = (__bf16*)alloc((size_t)MC * 384 * 2);   // LN tokens / attn out / mlp in
  __bf16* qkvb  = (__bf16*)alloc((size_t)MC * 1536 * 2);  // qkv (1152 used) / mlp hidden
  float*  seq2f = (float*)alloc((size_t)MC * 384 * 4);    // dwconv out f32; mlp2 accums in-place

  const int nchunks = NTOK / MC;
  const int wrc = MC / 392;   // window-rows per chunk

  convert_weights<<<6912, 256, 0, stream>>>(qkv_w, proj_w, w1, w2, wqb, wpb, w1b, w2b);
  ln_stats<<<dim3(13, NB_), 256, 0, stream>>>(x, meanb, rstdb);

  for (int ci = 0; ci < nchunks; ++ci) {
    const int q0 = ci * wrc;
    winrow_gather_ln<<<dim3(12, wrc), 256, 0, stream>>>(x, meanb, rstdb, ln_g, ln_b, xn, seqtok, q0);
    gemm_bt<0><<<dim3(9, MC / 128), 256, 0, stream>>>(xn, wqb, qkv_b, qkvb, MC, 1152, 384);
    attn_win<<<dim3(12, MC / 49), 64, 0, stream>>>(qkvb, btab, xn);
    gemm_bt<3><<<dim3(3, MC / 128), 256, 0, stream>>>(xn, wpb, proj_b,
        seqtok + (size_t)q0 * 392 * 384, MC, 384, 384);
  }

  for (int ci = 0; ci < nchunks; ++ci) {
    const int q0 = ci * wrc;
    dwconv_winrow<<<dim3(12, wrc), 256, 0, stream>>>(seqtok, conv_w, bn_g, bn_b, bn_m, bn_v,
                                                     xn, seq2f, q0);
    gemm_bt<1><<<dim3(12, MC / 128), 256, 0, stream>>>(xn, w1b, b1, qkvb, MC, 1536, 384);
    gemm_bt<4><<<dim3(3, MC / 128), 256, 0, stream>>>(qkvb, w2b, b2, seq2f, MC, 384, 1536);
    winrow_scatter<<<dim3(12, wrc), 256, 0, stream>>>(seq2f, out, q0);
  }
}